// Round 2
// baseline (318.738 us; speedup 1.0000x reference)
//
#include <hip/hip_runtime.h>
#include <cstdint>
#include <cstddef>

// ForwardAttention: B=32, T=2048, Q=K=V=512, A=128, TEMP=1
// d_out = [context 32x512 | fw 32x2048] f32  (81920 floats)
//
// Pipeline:
//  1) prep:    qp = query@Wq (fp32), WkT = bf16(Wk^T) [128][512]  -> ws
//  2) energy:  barrier-free bf16 MFMA GEMM (A-frags straight from HBM,
//              B-frags from L2) + tanh/We epilogue -> fw region of d_out
//  3) softmax: masked softmax + forward reweight + renorm, in-place
//  4) ctx_partial: t-split partial sums of fw[t]*values[t,:]      -> ws
//  5) ctx_reduce:  sum partials -> context region of d_out

#define T_ 2048
#define KD 512
#define AD 128

typedef __attribute__((ext_vector_type(8))) short bf16x8;
typedef __attribute__((ext_vector_type(4))) float f32x4;

__device__ __forceinline__ unsigned pack2bf(float a, float b) {
    unsigned ua = __float_as_uint(a), ub = __float_as_uint(b);
    ua += 0x7FFFu + ((ua >> 16) & 1u);   // RNE
    ub += 0x7FFFu + ((ub >> 16) & 1u);
    return (ua >> 16) | (ub & 0xFFFF0000u);
}

__device__ __forceinline__ f32x4 ntld4(const float* p) {
    return __builtin_nontemporal_load((const f32x4*)p);
}

// ---------------- kernel 1: qp + WkT(bf16) prep ----------------
__global__ __launch_bounds__(256) void prep_kernel(
    const float* __restrict__ query, const float* __restrict__ Wq,
    const float* __restrict__ Wk, float* __restrict__ qp,
    unsigned short* __restrict__ WkT)
{
    __shared__ float sq[128];
    const int tid = threadIdx.x;
    if (blockIdx.x < 32) {
        const int b = blockIdx.x;
        const int a = tid & 127, half = tid >> 7;
        const float* q = query + (size_t)b * KD + half * 256;
        const float* w = Wq + (size_t)(half * 256) * AD + a;
        float s0 = 0.f, s1 = 0.f, s2 = 0.f, s3 = 0.f;
        #pragma unroll 4
        for (int k = 0; k < 256; k += 4) {
            s0 += q[k + 0] * w[(size_t)(k + 0) * AD];
            s1 += q[k + 1] * w[(size_t)(k + 1) * AD];
            s2 += q[k + 2] * w[(size_t)(k + 2) * AD];
            s3 += q[k + 3] * w[(size_t)(k + 3) * AD];
        }
        float s = (s0 + s1) + (s2 + s3);
        if (half == 0) sq[a] = s;
        __syncthreads();
        if (half == 1) qp[(size_t)b * AD + a] = sq[a] + s;
    } else {
        const int blk2 = blockIdx.x - 32;      // 0..31, 16 k-rows each
        const int n = tid & 127, kr = tid >> 7;
        #pragma unroll
        for (int kk = 0; kk < 8; kk++) {
            int k = blk2 * 16 + kr * 8 + kk;
            float v = Wk[(size_t)k * AD + n];
            unsigned u = __float_as_uint(v);
            u += 0x7FFFu + ((u >> 16) & 1u);
            WkT[(size_t)n * KD + k] = (unsigned short)(u >> 16);
        }
    }
}

// ---------------- kernel 2: energies via bf16 MFMA, barrier-free ----------------
// M=65536 (b*2048+t), K=512, N=128. Block=4 waves, each wave owns 32 rows.
// A fragment (16x16x32): A[m=lane&15][k=quad*8+j] -> lane reads 8 contiguous
// fp32 from its keys row, packs to bf16 in-register. B fragment from WkT[n][k]
// (L2-resident) with the layout validated in round 1.
__global__ __launch_bounds__(256, 2) void energy_kernel(
    const float* __restrict__ keys, const unsigned short* __restrict__ WkT,
    const float* __restrict__ qp, const float* __restrict__ We,
    float* __restrict__ energy)
{
    const int tid = threadIdx.x;
    const int lane = tid & 63, wv = tid >> 6;
    const int lr = lane & 15, quad = lane >> 4;
    const int m0 = blockIdx.x * 128;
    const int b = m0 >> 11;

    const float* a0 = keys + (size_t)(m0 + wv * 32 + lr) * KD + quad * 8;
    const float* a1 = a0 + (size_t)16 * KD;
    const unsigned short* bp = WkT + (size_t)lr * KD + quad * 8;

    f32x4 acc[2][8];
    #pragma unroll
    for (int mt = 0; mt < 2; mt++)
        #pragma unroll
        for (int nt = 0; nt < 8; nt++)
            acc[mt][nt] = (f32x4){0.f, 0.f, 0.f, 0.f};

    for (int k0 = 0; k0 < KD; k0 += 64) {   // unrolled x2: 24 loads in flight
        f32x4 fa[2][4];
        bf16x8 bfr[2][8];
        #pragma unroll
        for (int h = 0; h < 2; h++) {
            const int kk = k0 + h * 32;
            fa[h][0] = ntld4(a0 + kk);
            fa[h][1] = ntld4(a0 + kk + 4);
            fa[h][2] = ntld4(a1 + kk);
            fa[h][3] = ntld4(a1 + kk + 4);
            #pragma unroll
            for (int nt = 0; nt < 8; nt++)
                bfr[h][nt] = *(const bf16x8*)(bp + (size_t)nt * 16 * KD + kk);
        }
        #pragma unroll
        for (int h = 0; h < 2; h++) {
            union { bf16x8 v; unsigned u[4]; } A0, A1;
            A0.u[0] = pack2bf(fa[h][0].x, fa[h][0].y);
            A0.u[1] = pack2bf(fa[h][0].z, fa[h][0].w);
            A0.u[2] = pack2bf(fa[h][1].x, fa[h][1].y);
            A0.u[3] = pack2bf(fa[h][1].z, fa[h][1].w);
            A1.u[0] = pack2bf(fa[h][2].x, fa[h][2].y);
            A1.u[1] = pack2bf(fa[h][2].z, fa[h][2].w);
            A1.u[2] = pack2bf(fa[h][3].x, fa[h][3].y);
            A1.u[3] = pack2bf(fa[h][3].z, fa[h][3].w);
            #pragma unroll
            for (int nt = 0; nt < 8; nt++) {
                acc[0][nt] = __builtin_amdgcn_mfma_f32_16x16x32_bf16(
                    A0.v, bfr[h][nt], acc[0][nt], 0, 0, 0);
                acc[1][nt] = __builtin_amdgcn_mfma_f32_16x16x32_bf16(
                    A1.v, bfr[h][nt], acc[1][nt], 0, 0, 0);
            }
        }
    }

    // epilogue: tanh + We-weighted row reduction (C/D: col=lane&15, row=quad*4+r)
    float part[2][4] = {{0.f, 0.f, 0.f, 0.f}, {0.f, 0.f, 0.f, 0.f}};
    #pragma unroll
    for (int nt = 0; nt < 8; nt++) {
        int col = nt * 16 + lr;
        float we = We[col];
        float q  = qp[(size_t)b * AD + col];
        #pragma unroll
        for (int mt = 0; mt < 2; mt++)
            #pragma unroll
            for (int r = 0; r < 4; r++) {
                float x = acc[mt][nt][r] + q;
                float e2 = __expf(2.0f * x);        // tanh(x)=1-2/(e^{2x}+1)
                float th = 1.0f - 2.0f / (e2 + 1.0f);
                part[mt][r] += we * th;
            }
    }
    #pragma unroll
    for (int mt = 0; mt < 2; mt++)
        #pragma unroll
        for (int r = 0; r < 4; r++) {
            float v = part[mt][r];
            v += __shfl_xor(v, 1); v += __shfl_xor(v, 2);
            v += __shfl_xor(v, 4); v += __shfl_xor(v, 8);
            if (lr == 0)
                energy[(size_t)m0 + wv * 32 + mt * 16 + quad * 4 + r] = v;
        }
}

// ---------------- kernel 3: softmax + forward attention (in-place) ----------------
__device__ __forceinline__ float blk_max16(float v, float* sred) {
    #pragma unroll
    for (int m = 1; m < 64; m <<= 1) v = fmaxf(v, __shfl_xor(v, m));
    if ((threadIdx.x & 63) == 0) sred[threadIdx.x >> 6] = v;
    __syncthreads();
    float r = sred[0];
    #pragma unroll
    for (int i = 1; i < 16; i++) r = fmaxf(r, sred[i]);
    __syncthreads();
    return r;
}
__device__ __forceinline__ float blk_sum16(float v, float* sred) {
    #pragma unroll
    for (int m = 1; m < 64; m <<= 1) v += __shfl_xor(v, m);
    if ((threadIdx.x & 63) == 0) sred[threadIdx.x >> 6] = v;
    __syncthreads();
    float r = 0.f;
    #pragma unroll
    for (int i = 0; i < 16; i++) r += sred[i];
    __syncthreads();
    return r;
}

__global__ __launch_bounds__(1024) void softmax_fw_kernel(
    const float* __restrict__ prev, const int* __restrict__ mask,
    float* __restrict__ fw)   // holds energies on entry
{
    __shared__ float sred[16];
    const int b = blockIdx.x, tid = threadIdx.x;
    const size_t base = (size_t)b * T_;
    float e[2];
    #pragma unroll
    for (int i = 0; i < 2; i++) {
        int t = tid + 1024 * i;
        float ev = fw[base + t];
        if (mask[base + t] == 0) ev = -__builtin_inff();
        e[i] = ev;
    }
    float mx = blk_max16(fmaxf(e[0], e[1]), sred);

    float ex[2];
    ex[0] = __expf(e[0] - mx); ex[1] = __expf(e[1] - mx);
    float s = blk_sum16(ex[0] + ex[1], sred);
    const float invS = 1.0f / s;

    float fwv[2]; float s2 = 0.f;
    #pragma unroll
    for (int i = 0; i < 2; i++) {
        int t = tid + 1024 * i;
        float pv = prev[base + t];
        float pm = (t == 0) ? 0.f : prev[base + t - 1];
        float r = ex[i] * invS;
        fwv[i] = (t == 0) ? r : r * (pv + pm);
        s2 += fwv[i];
    }
    s2 = blk_sum16(s2, sred);
    const float invD = 1.0f / (s2 + 1e-8f);
    #pragma unroll
    for (int i = 0; i < 2; i++)
        fw[base + tid + 1024 * i] = fwv[i] * invD;
}

// ---------------- kernel 4: context partials (t-split, 64 t per block) ----------------
__global__ __launch_bounds__(256) void ctx_partial_kernel(
    const float* __restrict__ values, const float* __restrict__ fw,
    float* __restrict__ part)
{
    __shared__ float sfw[64];
    __shared__ f32x4 sacc[128];
    const int b = blockIdx.x >> 5, ts = blockIdx.x & 31;
    const int tid = threadIdx.x;
    const int t0 = ts * 64;
    if (tid < 64) sfw[tid] = fw[(size_t)b * T_ + t0 + tid];
    __syncthreads();
    const int d4 = tid & 127, tp = tid >> 7;
    const f32x4* vp = (const f32x4*)values + ((size_t)b * T_ + t0 + tp) * 128 + d4;
    f32x4 acc = {0.f, 0.f, 0.f, 0.f};
    #pragma unroll 16
    for (int i = 0; i < 32; i++) {
        float f = sfw[tp + 2 * i];
        f32x4 v = __builtin_nontemporal_load(vp + (size_t)i * 256);
        acc.x += f * v.x; acc.y += f * v.y; acc.z += f * v.z; acc.w += f * v.w;
    }
    if (tp) sacc[d4] = acc;
    __syncthreads();
    if (!tp) {
        f32x4 o = sacc[d4];
        o.x += acc.x; o.y += acc.y; o.z += acc.z; o.w += acc.w;
        ((f32x4*)part)[(size_t)blockIdx.x * 128 + d4] = o;
    }
}

// ---------------- kernel 5: reduce partials -> context ----------------
__global__ __launch_bounds__(256) void ctx_reduce_kernel(
    const float* __restrict__ part, float* __restrict__ ctx)
{
    const int idx = blockIdx.x * 256 + threadIdx.x;  // 0..16383
    const int b = idx >> 9, d = idx & 511;
    float s = 0.f;
    #pragma unroll
    for (int ts = 0; ts < 32; ts++)
        s += part[((size_t)(b * 32 + ts)) * 512 + d];
    ctx[idx] = s;
}

extern "C" void kernel_launch(void* const* d_in, const int* in_sizes, int n_in,
                              void* d_out, int out_size, void* d_ws, size_t ws_size,
                              hipStream_t stream) {
    const float* query  = (const float*)d_in[0];
    const float* keys   = (const float*)d_in[1];
    const float* values = (const float*)d_in[2];
    const float* prev   = (const float*)d_in[3];
    const int*   mask   = (const int*)d_in[4];
    const float* Wq     = (const float*)d_in[5];
    const float* Wk     = (const float*)d_in[6];
    const float* We     = (const float*)d_in[7];

    float* ctx = (float*)d_out;          // 32*512
    float* fw  = ctx + 32 * 512;         // 32*2048 (doubles as energy buffer)

    float* wsf = (float*)d_ws;
    float* qp   = wsf;                                    // 4096 floats
    float* part = wsf + 4096;                             // 1024*512 = 524288 floats
    unsigned short* WkT = (unsigned short*)(wsf + 4096 + 524288);  // 65536 ushorts

    prep_kernel<<<dim3(64), dim3(256), 0, stream>>>(query, Wq, Wk, qp, WkT);
    energy_kernel<<<dim3(512), dim3(256), 0, stream>>>(keys, WkT, qp, We, fw);
    softmax_fw_kernel<<<dim3(32), dim3(1024), 0, stream>>>(prev, mask, fw);
    ctx_partial_kernel<<<dim3(1024), dim3(256), 0, stream>>>(values, fw, part);
    ctx_reduce_kernel<<<dim3(64), dim3(256), 0, stream>>>(part, ctx);
}

// Round 3
// 316.391 us; speedup vs baseline: 1.0074x; 1.0074x over previous
//
#include <hip/hip_runtime.h>
#include <cstdint>
#include <cstddef>

// ForwardAttention: B=32, T=2048, Q=K=V=512, A=128, TEMP=1
// d_out = [context 32x512 | fw 32x2048] f32  (81920 floats)
//
// Pipeline (4 launches):
//  1) prep:    qp = query@Wq (fp32, 16-acc ILP), WkT = bf16(Wk^T), zero ctx
//  2) energy:  barrier-free bf16 MFMA GEMM (A-frags straight from HBM,
//              B-frags from L2/L3) + tanh/We epilogue -> fw region of d_out
//  3) softmax: masked softmax + forward reweight + renorm, in-place
//  4) ctx:     t-split fw[t]*values[t,:] partials, atomicAdd into ctx

#define T_ 2048
#define KD 512
#define AD 128

typedef __attribute__((ext_vector_type(8))) short bf16x8;
typedef __attribute__((ext_vector_type(4))) float f32x4;

__device__ __forceinline__ unsigned pack2bf(float a, float b) {
    unsigned ua = __float_as_uint(a), ub = __float_as_uint(b);
    ua += 0x7FFFu + ((ua >> 16) & 1u);   // RNE
    ub += 0x7FFFu + ((ub >> 16) & 1u);
    return (ua >> 16) | (ub & 0xFFFF0000u);
}

__device__ __forceinline__ f32x4 ntld4(const float* p) {
    return __builtin_nontemporal_load((const f32x4*)p);
}

// ---------------- kernel 1: qp + WkT(bf16) prep + ctx zero ----------------
__global__ __launch_bounds__(256) void prep_kernel(
    const float* __restrict__ query, const float* __restrict__ Wq,
    const float* __restrict__ Wk, float* __restrict__ qp,
    unsigned short* __restrict__ WkT, float* __restrict__ ctx)
{
    __shared__ float sq[128];
    const int tid = threadIdx.x;
    // zero the context accumulator region (64 blocks x 256 = 16384 floats)
    ctx[blockIdx.x * 256 + tid] = 0.f;

    if (blockIdx.x < 32) {
        // qp[b][a] = sum_k query[b][k]*Wq[k][a]; 16 independent accumulators
        const int b = blockIdx.x;
        const int a = tid & 127, half = tid >> 7;
        const float* q = query + (size_t)b * KD + half * 256;
        const float* w = Wq + (size_t)(half * 256) * AD + a;
        float s[16];
        #pragma unroll
        for (int j = 0; j < 16; j++) s[j] = 0.f;
        for (int k = 0; k < 256; k += 16)
            #pragma unroll
            for (int j = 0; j < 16; j++)
                s[j] += q[k + j] * w[(size_t)(k + j) * AD];
        float t = 0.f;
        #pragma unroll
        for (int j = 0; j < 16; j++) t += s[j];
        if (half == 0) sq[a] = t;
        __syncthreads();
        if (half == 1) qp[(size_t)b * AD + a] = sq[a] + t;
    } else {
        // WkT[n][k] = bf16(Wk[k][n])
        const int blk2 = blockIdx.x - 32;      // 0..31, 16 k-rows each
        const int n = tid & 127, kr = tid >> 7;
        #pragma unroll
        for (int kk = 0; kk < 8; kk++) {
            int k = blk2 * 16 + kr * 8 + kk;
            float v = Wk[(size_t)k * AD + n];
            unsigned u = __float_as_uint(v);
            u += 0x7FFFu + ((u >> 16) & 1u);
            WkT[(size_t)n * KD + k] = (unsigned short)(u >> 16);
        }
    }
}

// ---------------- kernel 2: energies via bf16 MFMA, barrier-free ----------------
// M=65536 (b*2048+t), K=512, N=128. Block=4 waves, each wave owns 32 rows.
__global__ __launch_bounds__(256, 2) void energy_kernel(
    const float* __restrict__ keys, const unsigned short* __restrict__ WkT,
    const float* __restrict__ qp, const float* __restrict__ We,
    float* __restrict__ energy)
{
    const int tid = threadIdx.x;
    const int lane = tid & 63, wv = tid >> 6;
    const int lr = lane & 15, quad = lane >> 4;
    const int m0 = blockIdx.x * 128;
    const int b = m0 >> 11;

    const float* a0 = keys + (size_t)(m0 + wv * 32 + lr) * KD + quad * 8;
    const float* a1 = a0 + (size_t)16 * KD;
    const unsigned short* bp = WkT + (size_t)lr * KD + quad * 8;

    f32x4 acc[2][8];
    #pragma unroll
    for (int mt = 0; mt < 2; mt++)
        #pragma unroll
        for (int nt = 0; nt < 8; nt++)
            acc[mt][nt] = (f32x4){0.f, 0.f, 0.f, 0.f};

    for (int k0 = 0; k0 < KD; k0 += 64) {   // unrolled x2: 24 loads in flight
        f32x4 fa[2][4];
        bf16x8 bfr[2][8];
        #pragma unroll
        for (int h = 0; h < 2; h++) {
            const int kk = k0 + h * 32;
            fa[h][0] = ntld4(a0 + kk);
            fa[h][1] = ntld4(a0 + kk + 4);
            fa[h][2] = ntld4(a1 + kk);
            fa[h][3] = ntld4(a1 + kk + 4);
            #pragma unroll
            for (int nt = 0; nt < 8; nt++)
                bfr[h][nt] = *(const bf16x8*)(bp + (size_t)nt * 16 * KD + kk);
        }
        #pragma unroll
        for (int h = 0; h < 2; h++) {
            union { bf16x8 v; unsigned u[4]; } A0, A1;
            A0.u[0] = pack2bf(fa[h][0].x, fa[h][0].y);
            A0.u[1] = pack2bf(fa[h][0].z, fa[h][0].w);
            A0.u[2] = pack2bf(fa[h][1].x, fa[h][1].y);
            A0.u[3] = pack2bf(fa[h][1].z, fa[h][1].w);
            A1.u[0] = pack2bf(fa[h][2].x, fa[h][2].y);
            A1.u[1] = pack2bf(fa[h][2].z, fa[h][2].w);
            A1.u[2] = pack2bf(fa[h][3].x, fa[h][3].y);
            A1.u[3] = pack2bf(fa[h][3].z, fa[h][3].w);
            #pragma unroll
            for (int nt = 0; nt < 8; nt++) {
                acc[0][nt] = __builtin_amdgcn_mfma_f32_16x16x32_bf16(
                    A0.v, bfr[h][nt], acc[0][nt], 0, 0, 0);
                acc[1][nt] = __builtin_amdgcn_mfma_f32_16x16x32_bf16(
                    A1.v, bfr[h][nt], acc[1][nt], 0, 0, 0);
            }
        }
    }

    // epilogue: tanh + We-weighted row reduction (C/D: col=lane&15, row=quad*4+r)
    float part[2][4] = {{0.f, 0.f, 0.f, 0.f}, {0.f, 0.f, 0.f, 0.f}};
    #pragma unroll
    for (int nt = 0; nt < 8; nt++) {
        int col = nt * 16 + lr;
        float we = We[col];
        float q  = qp[(size_t)b * AD + col];
        #pragma unroll
        for (int mt = 0; mt < 2; mt++)
            #pragma unroll
            for (int r = 0; r < 4; r++) {
                float x = acc[mt][nt][r] + q;
                float e2 = __expf(2.0f * x);        // tanh(x)=1-2/(e^{2x}+1)
                float th = 1.0f - 2.0f / (e2 + 1.0f);
                part[mt][r] += we * th;
            }
    }
    #pragma unroll
    for (int mt = 0; mt < 2; mt++)
        #pragma unroll
        for (int r = 0; r < 4; r++) {
            float v = part[mt][r];
            v += __shfl_xor(v, 1); v += __shfl_xor(v, 2);
            v += __shfl_xor(v, 4); v += __shfl_xor(v, 8);
            if (lr == 0)
                energy[(size_t)m0 + wv * 32 + mt * 16 + quad * 4 + r] = v;
        }
}

// ---------------- kernel 3: softmax + forward attention (in-place) ----------------
__device__ __forceinline__ float blk_max16(float v, float* sred) {
    #pragma unroll
    for (int m = 1; m < 64; m <<= 1) v = fmaxf(v, __shfl_xor(v, m));
    if ((threadIdx.x & 63) == 0) sred[threadIdx.x >> 6] = v;
    __syncthreads();
    float r = sred[0];
    #pragma unroll
    for (int i = 1; i < 16; i++) r = fmaxf(r, sred[i]);
    __syncthreads();
    return r;
}
__device__ __forceinline__ float blk_sum16(float v, float* sred) {
    #pragma unroll
    for (int m = 1; m < 64; m <<= 1) v += __shfl_xor(v, m);
    if ((threadIdx.x & 63) == 0) sred[threadIdx.x >> 6] = v;
    __syncthreads();
    float r = 0.f;
    #pragma unroll
    for (int i = 0; i < 16; i++) r += sred[i];
    __syncthreads();
    return r;
}

__global__ __launch_bounds__(1024) void softmax_fw_kernel(
    const float* __restrict__ prev, const int* __restrict__ mask,
    float* __restrict__ fw)   // holds energies on entry
{
    __shared__ float sred[16];
    const int b = blockIdx.x, tid = threadIdx.x;
    const size_t base = (size_t)b * T_;
    float e[2];
    #pragma unroll
    for (int i = 0; i < 2; i++) {
        int t = tid + 1024 * i;
        float ev = fw[base + t];
        if (mask[base + t] == 0) ev = -__builtin_inff();
        e[i] = ev;
    }
    float mx = blk_max16(fmaxf(e[0], e[1]), sred);

    float ex[2];
    ex[0] = __expf(e[0] - mx); ex[1] = __expf(e[1] - mx);
    float s = blk_sum16(ex[0] + ex[1], sred);
    const float invS = 1.0f / s;

    float fwv[2]; float s2 = 0.f;
    #pragma unroll
    for (int i = 0; i < 2; i++) {
        int t = tid + 1024 * i;
        float pv = prev[base + t];
        float pm = (t == 0) ? 0.f : prev[base + t - 1];
        float r = ex[i] * invS;
        fwv[i] = (t == 0) ? r : r * (pv + pm);
        s2 += fwv[i];
    }
    s2 = blk_sum16(s2, sred);
    const float invD = 1.0f / (s2 + 1e-8f);
    #pragma unroll
    for (int i = 0; i < 2; i++)
        fw[base + tid + 1024 * i] = fwv[i] * invD;
}

// ---------------- kernel 4: context partials, atomicAdd into ctx ----------------
__global__ __launch_bounds__(256) void ctx_kernel(
    const float* __restrict__ values, const float* __restrict__ fw,
    float* __restrict__ ctx)
{
    __shared__ float sfw[64];
    __shared__ f32x4 sacc[128];
    const int b = blockIdx.x >> 5, ts = blockIdx.x & 31;
    const int tid = threadIdx.x;
    const int t0 = ts * 64;
    if (tid < 64) sfw[tid] = fw[(size_t)b * T_ + t0 + tid];
    __syncthreads();
    const int d4 = tid & 127, tp = tid >> 7;
    const f32x4* vp = (const f32x4*)values + ((size_t)b * T_ + t0 + tp) * 128 + d4;
    f32x4 acc = {0.f, 0.f, 0.f, 0.f};
    #pragma unroll 16
    for (int i = 0; i < 32; i++) {
        float f = sfw[tp + 2 * i];
        f32x4 v = __builtin_nontemporal_load(vp + (size_t)i * 256);
        acc.x += f * v.x; acc.y += f * v.y; acc.z += f * v.z; acc.w += f * v.w;
    }
    if (tp) sacc[d4] = acc;
    __syncthreads();
    if (!tp) {
        f32x4 o = sacc[d4];
        o.x += acc.x; o.y += acc.y; o.z += acc.z; o.w += acc.w;
        float* dst = ctx + (size_t)b * 512 + d4 * 4;
        unsafeAtomicAdd(dst + 0, o.x);
        unsafeAtomicAdd(dst + 1, o.y);
        unsafeAtomicAdd(dst + 2, o.z);
        unsafeAtomicAdd(dst + 3, o.w);
    }
}

extern "C" void kernel_launch(void* const* d_in, const int* in_sizes, int n_in,
                              void* d_out, int out_size, void* d_ws, size_t ws_size,
                              hipStream_t stream) {
    const float* query  = (const float*)d_in[0];
    const float* keys   = (const float*)d_in[1];
    const float* values = (const float*)d_in[2];
    const float* prev   = (const float*)d_in[3];
    const int*   mask   = (const int*)d_in[4];
    const float* Wq     = (const float*)d_in[5];
    const float* Wk     = (const float*)d_in[6];
    const float* We     = (const float*)d_in[7];

    float* ctx = (float*)d_out;          // 32*512 (atomic accumulator, zeroed by prep)
    float* fw  = ctx + 32 * 512;         // 32*2048 (doubles as energy buffer)

    float* wsf = (float*)d_ws;
    float* qp  = wsf;                                    // 4096 floats
    unsigned short* WkT = (unsigned short*)(wsf + 4096); // 65536 ushorts

    prep_kernel<<<dim3(64), dim3(256), 0, stream>>>(query, Wq, Wk, qp, WkT, ctx);
    energy_kernel<<<dim3(512), dim3(256), 0, stream>>>(keys, WkT, qp, We, fw);
    softmax_fw_kernel<<<dim3(32), dim3(1024), 0, stream>>>(prev, mask, fw);
    ctx_kernel<<<dim3(1024), dim3(256), 0, stream>>>(values, fw, ctx);
}